// Round 2
// baseline (154.115 us; speedup 1.0000x reference)
//
#include <hip/hip_runtime.h>
#include <hip/hip_bf16.h>

typedef short v8s __attribute__((ext_vector_type(8)));
typedef unsigned short v8u __attribute__((ext_vector_type(8)));
typedef float v4f __attribute__((ext_vector_type(4)));
typedef unsigned short u16;

#define LL 1024
#define DD 1024

static __device__ __forceinline__ u16 f2b(float x) {
  __hip_bfloat16 h = __float2bfloat16(x);
  return __builtin_bit_cast(u16, h);
}

static __device__ __forceinline__ void gload_lds16(const u16* g, u16* l) {
  __builtin_amdgcn_global_load_lds((const __attribute__((address_space(1))) void*)g,
                                   (__attribute__((address_space(3))) void*)l, 16, 0, 0);
}

// ---------------- f32 -> bf16 conversion (3 tensors per launch via grid.y) ----
__global__ __launch_bounds__(256) void cvt3(const float* __restrict__ p0,
                                            const float* __restrict__ p1,
                                            const float* __restrict__ p2,
                                            u16* __restrict__ out, int n8, long ostride) {
  const float* src = blockIdx.y == 0 ? p0 : (blockIdx.y == 1 ? p1 : p2);
  u16* dst = out + (long)blockIdx.y * ostride;
  int i = blockIdx.x * 256 + threadIdx.x;
  if (i >= n8) return;
  const float4* p = (const float4*)src + (long)i * 2;
  float4 a = p[0], b = p[1];
  v8u r;
  r[0] = f2b(a.x); r[1] = f2b(a.y); r[2] = f2b(a.z); r[3] = f2b(a.w);
  r[4] = f2b(b.x); r[5] = f2b(b.y); r[6] = f2b(b.z); r[7] = f2b(b.w);
  *((v8u*)dst + i) = r;
}

// ---------------- C[M,N] = A[M,K] * B[N,K]^T  (bf16 in, OUTT out) -------------
// 128x128 tile, BK=64, 4 waves (2x2), m97 structure: global_load_lds + 2 barriers.
template <typename OUTT>
__global__ __launch_bounds__(256) void gemm_bt(const u16* __restrict__ A,
                                               const u16* __restrict__ Bw,
                                               OUTT* __restrict__ C,
                                               long za, long zb, long zc) {
  __shared__ u16 As[128 * 64];
  __shared__ u16 Bs[128 * 64];
  A += (long)blockIdx.z * za;
  Bw += (long)blockIdx.z * zb;
  C += (long)blockIdx.z * zc;
  const int tid = threadIdx.x;
  const int lane = tid & 63;
  const int l15 = lane & 15, lg = lane >> 4;
  const int wid = tid >> 6;
  const int wm = wid >> 1, wn = wid & 1;
  const long mbase = (long)blockIdx.y * 128;
  const long nbase = (long)blockIdx.x * 128;

  const u16* ap = A + (mbase + (tid >> 3)) * 1024 + (tid & 7) * 8;
  const u16* bp = Bw + (nbase + (tid >> 3)) * 1024 + (tid & 7) * 8;

  v4f acc[4][4] = {};

  for (int kt = 0; kt < 16; ++kt) {
    __syncthreads();
#pragma unroll
    for (int j = 0; j < 4; ++j) {
      gload_lds16(ap + kt * 64 + j * 32 * 1024, &As[(tid + 256 * j) * 8]);
      gload_lds16(bp + kt * 64 + j * 32 * 1024, &Bs[(tid + 256 * j) * 8]);
    }
    __syncthreads();  // drains vmcnt -> LDS tiles ready
#pragma unroll
    for (int kk = 0; kk < 2; ++kk) {
      v8s a[4], b[4];
#pragma unroll
      for (int i = 0; i < 4; ++i)
        a[i] = *(const v8s*)&As[(wm * 64 + i * 16 + l15) * 64 + kk * 32 + lg * 8];
#pragma unroll
      for (int i = 0; i < 4; ++i)
        b[i] = *(const v8s*)&Bs[(wn * 64 + i * 16 + l15) * 64 + kk * 32 + lg * 8];
#pragma unroll
      for (int mi = 0; mi < 4; ++mi)
#pragma unroll
        for (int nj = 0; nj < 4; ++nj)
          acc[mi][nj] = __builtin_amdgcn_mfma_f32_16x16x32_bf16(a[mi], b[nj], acc[mi][nj], 0, 0, 0);
    }
  }
#pragma unroll
  for (int mi = 0; mi < 4; ++mi) {
#pragma unroll
    for (int r = 0; r < 4; ++r) {
      long row = mbase + wm * 64 + mi * 16 + lg * 4 + r;
#pragma unroll
      for (int nj = 0; nj < 4; ++nj) {
        long col = nbase + wn * 64 + nj * 16 + l15;
        if constexpr (__is_same(OUTT, float))
          C[row * 1024 + col] = acc[mi][nj][r];
        else
          C[row * 1024 + col] = f2b(acc[mi][nj][r]);
      }
    }
  }
}

// ---------------- fused masked attention ------------------------------------
// grid (16 qtiles, 64 bh). Block = 4 waves x 16 q-rows. Flash over 64-key tiles.
__global__ __launch_bounds__(256) void attn_kern(const u16* __restrict__ qb,
                                                 const u16* __restrict__ kb,
                                                 const u16* __restrict__ vb,
                                                 const int* __restrict__ valid,
                                                 u16* __restrict__ ob) {
  __shared__ u16 Ks[64 * 72];       // [key][hd], +8 pad vs 64 -> no 16-way conflict
  __shared__ u16 Vt[64 * 72];       // [hd][key], transposed for PV B-operand
  __shared__ u16 Ps[4][16 * 72];    // per-wave P tile [q][key]
  __shared__ int s_mv;

  const int tid = threadIdx.x;
  const int lane = tid & 63;
  const int wid = tid >> 6;
  const int l15 = lane & 15, lg = lane >> 4;
  const int bh = blockIdx.y;
  const int b = bh >> 4, h = bh & 15;
  const int qrow0 = blockIdx.x * 64 + wid * 16;
  const long headoff = ((long)b * LL) * DD + h * 64;

  // Q A-fragments live in registers for the whole kernel
  v8s qf[2];
#pragma unroll
  for (int ks = 0; ks < 2; ++ks)
    qf[ks] = *(const v8s*)(qb + headoff + (long)(qrow0 + l15) * DD + ks * 32 + lg * 8);

  // per-lane rows (C-frag rows lg*4+r): raw valid (mask) and effective (loop bound)
  int vraw[4];
  int mymax = 1;
#pragma unroll
  for (int r = 0; r < 4; ++r) {
    int v = valid[bh * LL + qrow0 + lg * 4 + r];
    vraw[r] = v;
    mymax = max(mymax, v == 0 ? LL : v);  // valid==0 => all-masked => need all tiles
  }
  if (tid == 0) s_mv = 1;
  int wmax = mymax;
#pragma unroll
  for (int d = 1; d < 64; d <<= 1) wmax = max(wmax, __shfl_xor(wmax, d));
  __syncthreads();
  if (lane == 0) atomicMax(&s_mv, wmax);
  __syncthreads();
  const int ntiles = (s_mv + 63) >> 6;

  float mrow[4], lrow[4];
  v4f oacc[4] = {};
#pragma unroll
  for (int r = 0; r < 4; ++r) { mrow[r] = -1e30f; lrow[r] = 0.0f; }

  const int kk = tid & 63;   // staging: key row
  const int qtr = tid >> 6;  // staging: 16-wide hd quarter

  for (int kt = 0; kt < ntiles; ++kt) {
    __syncthreads();  // previous tile fully consumed
    {
      const long rowoff = headoff + (long)(kt * 64 + kk) * DD + qtr * 16;
      v8s k0 = *(const v8s*)(kb + rowoff);
      v8s k1 = *(const v8s*)(kb + rowoff + 8);
      v8s v0 = *(const v8s*)(vb + rowoff);
      v8s v1 = *(const v8s*)(vb + rowoff + 8);
      *(v8s*)&Ks[kk * 72 + qtr * 16] = k0;
      *(v8s*)&Ks[kk * 72 + qtr * 16 + 8] = k1;
      v8u u0 = __builtin_bit_cast(v8u, v0);
      v8u u1 = __builtin_bit_cast(v8u, v1);
#pragma unroll
      for (int j = 0; j < 8; ++j) Vt[(qtr * 16 + j) * 72 + kk] = u0[j];
#pragma unroll
      for (int j = 0; j < 8; ++j) Vt[(qtr * 16 + 8 + j) * 72 + kk] = u1[j];
    }
    __syncthreads();

    // S = Q K^T for 16 q rows x 64 keys
    v4f s[4];
#pragma unroll
    for (int t = 0; t < 4; ++t) {
      v4f z = {};
#pragma unroll
      for (int ks = 0; ks < 2; ++ks) {
        v8s kf = *(const v8s*)&Ks[(t * 16 + l15) * 72 + ks * 32 + lg * 8];
        z = __builtin_amdgcn_mfma_f32_16x16x32_bf16(qf[ks], kf, z, 0, 0, 0);
      }
      s[t] = z;
    }

    // scale + mask (exact reference semantics: -1e6, col < valid_raw)
    const int colbase = kt * 64 + l15;
#pragma unroll
    for (int t = 0; t < 4; ++t)
#pragma unroll
      for (int r = 0; r < 4; ++r) {
        float val = s[t][r] * 0.125f;
        s[t][r] = (colbase + t * 16 < vraw[r]) ? val : -1e6f;
      }

    // online softmax: row max over 64 keys (16-lane shfl groups hold same rows)
    float pm[4];
#pragma unroll
    for (int r = 0; r < 4; ++r)
      pm[r] = fmaxf(fmaxf(s[0][r], s[1][r]), fmaxf(s[2][r], s[3][r]));
#pragma unroll
    for (int d = 1; d < 16; d <<= 1)
#pragma unroll
      for (int r = 0; r < 4; ++r) pm[r] = fmaxf(pm[r], __shfl_xor(pm[r], d));

    float sc[4];
#pragma unroll
    for (int r = 0; r < 4; ++r) {
      float mn = fmaxf(mrow[r], pm[r]);
      sc[r] = __expf(mrow[r] - mn);
      mrow[r] = mn;
    }
    float rs[4] = {0.f, 0.f, 0.f, 0.f};
#pragma unroll
    for (int t = 0; t < 4; ++t)
#pragma unroll
      for (int r = 0; r < 4; ++r) {
        float p = __expf(s[t][r] - mrow[r]);
        s[t][r] = p;
        rs[r] += p;
      }
#pragma unroll
    for (int d = 1; d < 16; d <<= 1)
#pragma unroll
      for (int r = 0; r < 4; ++r) rs[r] += __shfl_xor(rs[r], d);
#pragma unroll
    for (int r = 0; r < 4; ++r) lrow[r] = lrow[r] * sc[r] + rs[r];
#pragma unroll
    for (int t = 0; t < 4; ++t)
#pragma unroll
      for (int r = 0; r < 4; ++r) oacc[t][r] *= sc[r];

    // P -> bf16 -> per-wave LDS, then consume as MFMA A-operand
#pragma unroll
    for (int t = 0; t < 4; ++t)
#pragma unroll
      for (int r = 0; r < 4; ++r)
        Ps[wid][(lg * 4 + r) * 72 + t * 16 + l15] = f2b(s[t][r]);

    asm volatile("s_waitcnt lgkmcnt(0)" ::: "memory");
    __builtin_amdgcn_sched_barrier(0);

#pragma unroll
    for (int ks = 0; ks < 2; ++ks) {
      v8s pa = *(const v8s*)&Ps[wid][l15 * 72 + ks * 32 + lg * 8];
#pragma unroll
      for (int t = 0; t < 4; ++t) {
        v8s vf = *(const v8s*)&Vt[(t * 16 + l15) * 72 + ks * 32 + lg * 8];
        oacc[t] = __builtin_amdgcn_mfma_f32_16x16x32_bf16(pa, vf, oacc[t], 0, 0, 0);
      }
    }
  }

  // epilogue: divide by row sums, write merged-head bf16 [B*L, D]
#pragma unroll
  for (int r = 0; r < 4; ++r) {
    float inv = 1.0f / lrow[r];
    long rp = headoff + (long)(qrow0 + lg * 4 + r) * DD;
#pragma unroll
    for (int t = 0; t < 4; ++t)
      ob[rp + t * 16 + l15] = f2b(oacc[t][r] * inv);
  }
}

// ---------------- launch ------------------------------------------------------
extern "C" void kernel_launch(void* const* d_in, const int* in_sizes, int n_in,
                              void* d_out, int out_size, void* d_ws, size_t ws_size,
                              hipStream_t stream) {
  const float* Q = (const float*)d_in[0];
  const float* K = (const float*)d_in[1];
  const float* V = (const float*)d_in[2];
  const int* valid = (const int*)d_in[3];
  const float* Wq = (const float*)d_in[4];
  const float* Wk = (const float*)d_in[5];
  const float* Wv = (const float*)d_in[6];
  const float* Wo = (const float*)d_in[7];
  float* out = (float*)d_out;

  u16* ws = (u16*)d_ws;
  const long MK = 4096L * 1024;  // Q/K/V rows x D
  const long NK = 1024L * 1024;  // weight
  u16* qkvb = ws;              // bf16 Q,K,V        3*MK
  u16* wqkv = qkvb + 3 * MK;   // bf16 Wq,Wk,Wv     3*NK
  u16* wo = wqkv + 3 * NK;     // bf16 Wo           NK
  u16* proj = wo + NK;         // q,k,v projections 3*MK
  u16* ob = proj + 3 * MK;     // attention output  MK

  cvt3<<<dim3(2048, 3), 256, 0, stream>>>(Q, K, V, qkvb, (int)(MK / 8), MK);
  cvt3<<<dim3(512, 3), 256, 0, stream>>>(Wq, Wk, Wv, wqkv, (int)(NK / 8), NK);
  cvt3<<<dim3(512, 1), 256, 0, stream>>>(Wo, Wo, Wo, wo, (int)(NK / 8), 0);

  gemm_bt<u16><<<dim3(8, 32, 3), 256, 0, stream>>>(qkvb, wqkv, proj, MK, NK, MK);
  attn_kern<<<dim3(16, 64), 256, 0, stream>>>(proj, proj + MK, proj + 2 * MK, valid, ob);
  gemm_bt<float><<<dim3(8, 32, 1), 256, 0, stream>>>(ob, wo, out, 0, 0, 0);
}